// Round 10
// baseline (669.971 us; speedup 1.0000x reference)
//
#include <hip/hip_runtime.h>

#define DEVINL __device__ __forceinline__

typedef _Float16 f16_t;
typedef _Float16 f16x8 __attribute__((ext_vector_type(8)));
typedef float    f32x4 __attribute__((ext_vector_type(4)));
typedef unsigned long long u64;

static constexpr int SEQ  = 512;   // sequence length
static constexpr int BT   = 16;    // batch rows per block (= MFMA M)
static constexpr int NW   = 8;     // waves per block
static constexpr int RING = 128;   // ring capacity (steps)

// f16-element offsets of the three layer-boundary streams in d_ws
static constexpr size_t S0_OFF = 0;                          // L0->L1: 64*128*2048
static constexpr size_t S1_OFF = (size_t)64 * RING * 2048;   // L1->L2
static constexpr size_t S2_OFF = S1_OFF * 2;                 // L2->L3: 64*128*1024
static constexpr size_t FLAG_OFF_B = 88080384;               // byte offset of flags

DEVINL f32x4 mfma16(f16x8 a, f16x8 b, f32x4 c) {
  return __builtin_amdgcn_mfma_f32_16x16x32_f16(a, b, c, 0, 0, 0);
}

// LDS-only barrier: never drain vmcnt inside the step loop
DEVINL void sync_raw() {
  asm volatile("s_waitcnt lgkmcnt(0)" ::: "memory");
  __builtin_amdgcn_s_barrier();
  asm volatile("" ::: "memory");
}
DEVINL void sync_full() {
  asm volatile("s_waitcnt vmcnt(0) lgkmcnt(0)" ::: "memory");
  __builtin_amdgcn_s_barrier();
  asm volatile("" ::: "memory");
}

// ---- flags ----
DEVINL int  ld_flag(const int* p) { return __hip_atomic_load(p, __ATOMIC_RELAXED, __HIP_MEMORY_SCOPE_AGENT); }
DEVINL void st_flag(int* p, int v) { __hip_atomic_store(p, v, __ATOMIC_RELAXED, __HIP_MEMORY_SCOPE_AGENT); }
DEVINL void wait_ge(const int* p, int tgt) {
  while (ld_flag(p) < tgt) __builtin_amdgcn_s_sleep(2);
}

// ---- hot-loop data path: plain cache-bypassing asm ops (MALL-coherent) ----
DEVINL void gl_load16_coh(const f16_t* p, f16x8& r) {
  asm volatile("global_load_dwordx4 %0, %1, off sc0 sc1"
               : "=&v"(r) : "v"(p) : "memory");
}
DEVINL void gl_load32_f32(const float* p, f32x4& a, f32x4& b) {  // cached (immutable input)
  asm volatile("global_load_dwordx4 %0, %2, off\n\t"
               "global_load_dwordx4 %1, %2, off offset:16"
               : "=&v"(a), "=&v"(b) : "v"(p) : "memory");
}
DEVINL void gl_store8_coh(void* p, u64 v) {
  asm volatile("global_store_dwordx2 %0, %1, off sc0 sc1"
               :: "v"(p), "v"(v) : "memory");
}

// One pipeline stage: layer l for one 16-row batch tile, all 512 steps.
//
// R10 step order:
//   ph0 ds_read stream value (lgkm latency covered by ph3 MFMAs)
//   ph2 x-load issue(t+2)   ph3 h-MFMAs   ph3.5 stream store(t-1)
//   ph4 gates+h-write       ph5 counted vmcnt   ph6 x-MFMAs (C = bias_acc)
//   ph7 barrier
// vmcnt invariant (per wave, per-step VMEM order = [4 loads, 1 store]):
// after ph5(t), outstanding = [L(t+2)x4, S(t)]; ph5(t) retired [L(t+1)x4,
// S(t-1)] -> at boundary t0 every store <= S(t0-2) (slot t0-3) retired by all
// waves behind the barrier -> publish P = t0-3 with no drain.
template<int LIN, int H, int XMODE, bool PROD, bool CONS, bool LAST>
DEVINL void run_layer(const float* __restrict__ wih, const float* __restrict__ whh,
                      const float* __restrict__ bih, const float* __restrict__ bhh,
                      const float* __restrict__ x0,
                      const f16_t* __restrict__ sin_, f16_t* __restrict__ sout_,
                      const int* prog_up, int* cons_self,
                      int* prog_self, const int* cons_down,
                      int b0, f16_t* hbA, f16_t* hbB, float* h_fin)
{
  constexpr int H16   = H/16;
  constexpr int KX    = (XMODE==0) ? 1 : LIN/32;
  constexpr int KH    = H/32;
  constexpr int SLI   = 16*LIN;               // input slot elems (XMODE1)
  constexpr int SLO   = 16*H;                 // output slot elems
  constexpr int NLOAD = (XMODE==0) ? 2 : KX;  // asm load ops per step

  const int tid = (int)threadIdx.x;
  const int wv = tid >> 6, ln = tid & 63, lr = ln & 15, lg = ln >> 4;
  const bool act = (wv < H16);
  const int j = wv*16 + lr;                    // this lane's hidden col

  // ---- weight B-fragments: wf[gate][kt], lane holds col n=g*H+j, k=kt*32+lg*8+i ----
  f16x8 wf[4][KX+KH];
  f32x4 bias_acc[4];                           // persistent MFMA C-init (bias splat)
  if (act) {
    #pragma unroll
    for (int g = 0; g < 4; ++g) {
      const int n = g*H + j;
      const float bv = bih[n] + bhh[n];
      bias_acc[g] = f32x4{bv, bv, bv, bv};
      #pragma unroll
      for (int kt = 0; kt < KX; ++kt)
        #pragma unroll
        for (int i = 0; i < 8; ++i) {
          const int k = kt*32 + lg*8 + i;
          wf[g][kt][i] = (f16_t)((k < LIN) ? wih[n*LIN + k] : 0.0f);  // L0 pads 8->32
        }
      #pragma unroll
      for (int kt = 0; kt < KH; ++kt)
        #pragma unroll
        for (int i = 0; i < 8; ++i)
          wf[g][KX+kt][i] = (f16_t)whh[n*H + kt*32 + lg*8 + i];
    }
  }

  for (int z = tid; z < BT*H; z += NW*64) { hbA[z] = (f16_t)0.0f; hbB[z] = (f16_t)0.0f; }
  float c4[4] = {0.0f, 0.0f, 0.0f, 0.0f};

  auto issue_loads = [&](int t, f16x8 (&xr)[KX], f32x4 (&pr)[2]) {
    if constexpr (XMODE == 0) {
      const float* p = x0 + ((size_t)(b0+lr)*SEQ + t)*8;
      gl_load32_f32(p, pr[0], pr[1]);
    } else {
      const f16_t* base = sin_ + (size_t)(t & (RING-1))*SLI + lr*LIN;
      #pragma unroll
      for (int kt = 0; kt < KX; ++kt) {
        const int chunk = ((kt*4 + lg) ^ (lr & 7)) * 8;    // swizzle folded in
        gl_load16_coh(base + chunk, xr[kt]);
      }
    }
  };

  // ---- initial consumer gate: covers prologue + first prefetches (x<=3) ----
  int fl_up = 0, fl_dn = 0;
  if constexpr (CONS) { wait_ge(prog_up, 7); fl_up = ld_flag(prog_up); }

  // ---- prologue: accA = bias + x_0 path; then issue loads for x_1 ----
  f32x4 accA[4], accB[4];
  f16x8 xA[KX], xB[KX];
  f32x4 pA[2], pB[2];
  if (act) {
    f16x8 x0f[KX]; f32x4 p0[2];
    issue_loads(0, x0f, p0);
    asm volatile("s_waitcnt vmcnt(0)" ::: "memory");
    __builtin_amdgcn_sched_barrier(0);
    if constexpr (XMODE == 0) {
      f16x8 xf;
      #pragma unroll
      for (int i = 0; i < 8; ++i) {
        const float v = (lg == 0) ? ((i < 4) ? p0[0][i] : p0[1][i-4]) : 0.0f;
        xf[i] = (f16_t)v;
      }
      #pragma unroll
      for (int g = 0; g < 4; ++g) accA[g] = mfma16(xf, wf[g][0], bias_acc[g]);
    } else {
      #pragma unroll
      for (int g = 0; g < 4; ++g) accA[g] = mfma16(x0f[0], wf[g][0], bias_acc[g]);
      #pragma unroll
      for (int kt = 1; kt < KX; ++kt)
        #pragma unroll
        for (int g = 0; g < 4; ++g) accA[g] = mfma16(x0f[kt], wf[g][kt], accA[g]);
    }
    issue_loads(1, xA, pA);
  }
  __syncthreads();

  constexpr float K1 = 1.442695040888963f;   // log2(e)
  constexpr float K2 = 2.885390081777927f;   // 2*log2(e)

  auto step = [&](int t, f32x4 (&ac)[4], f32x4 (&an)[4],
                  f16x8 (&xc)[KX], f32x4 (&pc)[2],
                  f16x8 (&xn)[KX], f32x4 (&pn)[2],
                  f16_t* hr, f16_t* hw) {
    if (act) {
      // ph0: EARLY ds_read of the stream-copy value (latency hidden by ph3)
      u64 sv = 0;
      if constexpr (PROD) { if (t >= 1) sv = *(const u64*)(hr + (size_t)tid*4); }
      // ph2: issue x prefetch for t+2
      const int tf = (t+2 < SEQ) ? t+2 : SEQ-1;
      issue_loads(tf, xn, pn);
      // ph3: h-path MFMAs (LDS only)
      #pragma unroll
      for (int kt = 0; kt < KH; ++kt) {
        const int chunk = ((kt*4 + lg) ^ (lr & 7)) * 8;
        const f16x8 ah = *(const f16x8*)&hr[lr*H + chunk];
        #pragma unroll
        for (int g = 0; g < 4; ++g) ac[g] = mfma16(ah, wf[g][KX+kt], ac[g]);
      }
      // ph3.5: stream store (sv ready long ago; store is issued AFTER the loads
      // — vmcnt invariant re-derived in header comment, publish math unchanged)
      if constexpr (PROD) {
        if (t >= 1)
          gl_store8_coh((u64*)(sout_ + (size_t)((t-1) & (RING-1))*SLO) + tid, sv);
      }
      // ph4: gates (depend only on ac) — 5 exp2 + 2 rcp; write h(t) to LDS
      #pragma unroll
      for (int r = 0; r < 4; ++r) {
        const int b = lg*4 + r;
        const float ei = __builtin_amdgcn_exp2f(-K1*ac[0][r]);
        const float ef = __builtin_amdgcn_exp2f(-K1*ac[1][r]);
        const float eg = __builtin_amdgcn_exp2f(-K2*fmaxf(ac[2][r], -42.f));
        const float eo = __builtin_amdgcn_exp2f(-K1*ac[3][r]);
        const float pig = (1.f + ei)*(1.f + eg);
        // cv = c/(1+ef) + (1-eg)/pig  via common denominator (one rcp)
        const float cv = (c4[r]*pig + (1.f - eg)*(1.f + ef))
                         * __builtin_amdgcn_rcpf((1.f + ef)*pig);
        c4[r] = cv;
        const float ec = __builtin_amdgcn_exp2f(-K2*fmaxf(cv, -42.f));
        const float h  = (1.f - ec) * __builtin_amdgcn_rcpf((1.f + eo)*(1.f + ec));
        hw[b*H + (j ^ ((b & 7) << 3))] = (f16_t)h;
        if constexpr (LAST) if (t == SEQ-1) h_fin[b*64 + j] = h;
      }
      // ph5: counted wait — retires x(t+1) loads (issued t-1) + store(t-1)
      if constexpr (PROD) {
        if (t >= 1) { asm volatile("s_waitcnt vmcnt(%0)" :: "i"(NLOAD+1) : "memory"); }
        else        { asm volatile("s_waitcnt vmcnt(%0)" :: "i"(NLOAD)   : "memory"); }
      } else {
        asm volatile("s_waitcnt vmcnt(%0)" :: "i"(NLOAD) : "memory");
      }
      __builtin_amdgcn_sched_barrier(0);
      // ph6: next-step acc: x_{t+1} path, C-init folded into first MFMA
      if constexpr (XMODE == 0) {
        f16x8 xf;
        #pragma unroll
        for (int i = 0; i < 8; ++i) {
          const float v = (lg == 0) ? ((i < 4) ? pc[0][i] : pc[1][i-4]) : 0.0f;
          xf[i] = (f16_t)v;
        }
        #pragma unroll
        for (int g = 0; g < 4; ++g) an[g] = mfma16(xf, wf[g][0], bias_acc[g]);
      } else {
        #pragma unroll
        for (int g = 0; g < 4; ++g) an[g] = mfma16(xc[0], wf[g][0], bias_acc[g]);
        #pragma unroll
        for (int kt = 1; kt < KX; ++kt)
          #pragma unroll
          for (int g = 0; g < 4; ++g) an[g] = mfma16(xc[kt], wf[g][kt], an[g]);
      }
    }
    sync_raw();   // ph7
  };

  // 2-step chunks: producer publishes every 2; consumer checks every 4
  // (tgt t0+5 vs flag prefetched 4 steps earlier); back-pressure every 8
  // (RING slack 16 - producer advance 8 = margin 8, still safe).
  for (int t0 = 0; t0 < SEQ; t0 += 2) {
    if (t0 > 0) {
      if constexpr (PROD) if (tid == 0) st_flag(prog_self, t0 - 3);
      if constexpr (CONS) {
        if ((t0 & 15) == 0 && tid == 0) st_flag(cons_self, t0 - 1);
        if ((t0 & 3) == 0) {
          const int tgt = (t0+5 < SEQ-1) ? t0+5 : SEQ-1;
          if (fl_up < tgt) wait_ge(prog_up, tgt);
          fl_up = ld_flag(prog_up);               // prefetch next check
        }
      }
      if constexpr (PROD) {
        if (t0 >= 112 && (t0 & 7) == 0) {         // ring slot-reuse safety
          const int tgt2 = t0 - 112;
          if (fl_dn < tgt2) wait_ge(cons_down, tgt2);
          fl_dn = ld_flag(cons_down);
        }
      }
    }
    step(t0,   accA, accB, xA, pA, xB, pB, hbB, hbA);
    step(t0+1, accB, accA, xB, pB, xA, pA, hbA, hbB);
  }

  // EPILOGUE: stream h(SEQ-1) (loop's shifted copy never emits it). t=511 odd -> hbB.
  if constexpr (PROD) {
    if (act) {
      const u64 v = *(const u64*)(hbB + (size_t)tid*4);
      gl_store8_coh((u64*)(sout_ + (size_t)((SEQ-1) & (RING-1))*SLO) + tid, v);
    }
  }
  sync_full();
  if (tid == 0) {
    if constexpr (PROD) st_flag(prog_self, SEQ);
    if constexpr (CONS) st_flag(cons_self, SEQ);
  }
}

extern "C" __global__ void lstm_init_flags(int* f) {
  const int i = (int)blockIdx.x * (int)blockDim.x + (int)threadIdx.x;
  if (i < 6144) f[i] = 0;
}

// 256 blocks: (bid&3)=layer, (bid>>2)=batch tile. One block/CU -> all resident.
extern "C" __global__ __launch_bounds__(512, 2)
void lstm_pipe(const float* __restrict__ xin,
  const float* w0i, const float* w0h, const float* b0i, const float* b0h,
  const float* w1i, const float* w1h, const float* b1i, const float* b1h,
  const float* w2i, const float* w2h, const float* b2i, const float* b2h,
  const float* w3i, const float* w3h, const float* b3i, const float* b3h,
  const float* __restrict__ lw, const float* __restrict__ lb,
  float* __restrict__ out, f16_t* ws16, int* flags)
{
  __shared__ __align__(16) f16_t hbuf0[BT*128];
  __shared__ __align__(16) f16_t hbuf1[BT*128];
  __shared__ float h_fin[BT*64];

  const int bid = (int)blockIdx.x;
  const int l = bid & 3, bt = bid >> 2, b0 = bt * BT;
  int* progf = flags;
  int* consf = flags + 3*64*16;
  int* P0 = progf + (0*64+bt)*16; int* C0 = consf + (0*64+bt)*16;
  int* P1 = progf + (1*64+bt)*16; int* C1 = consf + (1*64+bt)*16;
  int* P2 = progf + (2*64+bt)*16; int* C2 = consf + (2*64+bt)*16;

  f16_t* s0 = ws16 + S0_OFF + (size_t)bt * RING * 2048;
  f16_t* s1 = ws16 + S1_OFF + (size_t)bt * RING * 2048;
  f16_t* s2 = ws16 + S2_OFF + (size_t)bt * RING * 1024;

  if (l == 0) {
    run_layer<8,   128, 0, true,  false, false>(w0i,w0h,b0i,b0h, xin, nullptr, s0,
        nullptr, nullptr, P0, C0, b0, hbuf0, hbuf1, h_fin);
  } else if (l == 1) {
    run_layer<128, 128, 1, true,  true,  false>(w1i,w1h,b1i,b1h, nullptr, s0, s1,
        P0, C0, P1, C1, b0, hbuf0, hbuf1, h_fin);
  } else if (l == 2) {
    run_layer<128, 64,  1, true,  true,  false>(w2i,w2h,b2i,b2h, nullptr, s1, s2,
        P1, C1, P2, C2, b0, hbuf0, hbuf1, h_fin);
  } else {
    run_layer<64,  64,  1, false, true,  true >(w3i,w3h,b3i,b3h, nullptr, s2, nullptr,
        P2, C2, nullptr, nullptr, b0, hbuf0, hbuf1, h_fin);
    // final linear: out[b] = h_fin[b,:] . lw + lb
    const int wv = (int)threadIdx.x >> 6;
    const int ln = (int)threadIdx.x & 63;
    #pragma unroll
    for (int rr = 0; rr < 2; ++rr) {
      const int row = wv*2 + rr;
      float v = h_fin[row*64 + ln] * lw[ln];
      #pragma unroll
      for (int m = 32; m >= 1; m >>= 1) v += __shfl_xor(v, m, 64);
      if (ln == 0) out[b0 + row] = v + lb[0];
    }
  }
}

extern "C" void kernel_launch(void* const* d_in, const int* in_sizes, int n_in,
                              void* d_out, int out_size, void* d_ws, size_t ws_size,
                              hipStream_t stream) {
  const float* xin = (const float*)d_in[0];
  const float* w0i = (const float*)d_in[1];
  const float* w0h = (const float*)d_in[2];
  const float* b0i = (const float*)d_in[3];
  const float* b0h = (const float*)d_in[4];
  const float* w1i = (const float*)d_in[5];
  const float* w1h = (const float*)d_in[6];
  const float* b1i = (const float*)d_in[7];
  const float* b1h = (const float*)d_in[8];
  const float* w2i = (const float*)d_in[9];
  const float* w2h = (const float*)d_in[10];
  const float* b2i = (const float*)d_in[11];
  const float* b2h = (const float*)d_in[12];
  const float* w3i = (const float*)d_in[13];
  const float* w3h = (const float*)d_in[14];
  const float* b3i = (const float*)d_in[15];
  const float* b3h = (const float*)d_in[16];
  const float* lw  = (const float*)d_in[17];
  const float* lb  = (const float*)d_in[18];
  float* out = (float*)d_out;

  f16_t* ws16 = (f16_t*)d_ws;                       // ~80 MB streams
  int* flags  = (int*)((char*)d_ws + FLAG_OFF_B);   // 24 KB flags

  lstm_init_flags<<<12, 512, 0, stream>>>(flags);   // re-zero per launch (replay-safe)
  lstm_pipe<<<256, 512, 0, stream>>>(xin,
      w0i,w0h,b0i,b0h, w1i,w1h,b1i,b1h, w2i,w2h,b2i,b2h, w3i,w3h,b3i,b3h,
      lw, lb, out, ws16, flags);
}

// Round 11
// 634.014 us; speedup vs baseline: 1.0567x; 1.0567x over previous
//
#include <hip/hip_runtime.h>

#define DEVINL __device__ __forceinline__

typedef _Float16 f16_t;
typedef _Float16 f16x8 __attribute__((ext_vector_type(8)));
typedef float    f32x4 __attribute__((ext_vector_type(4)));
typedef unsigned long long u64;

static constexpr int SEQ  = 512;   // sequence length
static constexpr int BT   = 16;    // batch rows per block (= MFMA M)
static constexpr int NW   = 8;     // waves per block
static constexpr int RING = 128;   // ring capacity (steps)

// f16-element offsets of the three layer-boundary streams in d_ws
static constexpr size_t S0_OFF = 0;                          // L0->L1: 64*128*2048
static constexpr size_t S1_OFF = (size_t)64 * RING * 2048;   // L1->L2
static constexpr size_t S2_OFF = S1_OFF * 2;                 // L2->L3: 64*128*1024
static constexpr size_t FLAG_OFF_B = 88080384;               // byte offset of flags

DEVINL f32x4 mfma16(f16x8 a, f16x8 b, f32x4 c) {
  return __builtin_amdgcn_mfma_f32_16x16x32_f16(a, b, c, 0, 0, 0);
}

// LDS-only barrier: never drain vmcnt inside the step loop
DEVINL void sync_raw() {
  asm volatile("s_waitcnt lgkmcnt(0)" ::: "memory");
  __builtin_amdgcn_s_barrier();
  asm volatile("" ::: "memory");
}
DEVINL void sync_full() {
  asm volatile("s_waitcnt vmcnt(0) lgkmcnt(0)" ::: "memory");
  __builtin_amdgcn_s_barrier();
  asm volatile("" ::: "memory");
}

// ---- flags ----
DEVINL int  ld_flag(const int* p) { return __hip_atomic_load(p, __ATOMIC_RELAXED, __HIP_MEMORY_SCOPE_AGENT); }
DEVINL void st_flag(int* p, int v) { __hip_atomic_store(p, v, __ATOMIC_RELAXED, __HIP_MEMORY_SCOPE_AGENT); }
DEVINL void wait_ge(const int* p, int tgt) {
  while (ld_flag(p) < tgt) __builtin_amdgcn_s_sleep(2);
}

// ---- hot-loop data path: plain cache-bypassing asm ops (MALL-coherent) ----
DEVINL void gl_load16_coh(const f16_t* p, f16x8& r) {
  asm volatile("global_load_dwordx4 %0, %1, off sc0 sc1"
               : "=&v"(r) : "v"(p) : "memory");
}
DEVINL void gl_load32_f32(const float* p, f32x4& a, f32x4& b) {  // cached (immutable input)
  asm volatile("global_load_dwordx4 %0, %2, off\n\t"
               "global_load_dwordx4 %1, %2, off offset:16"
               : "=&v"(a), "=&v"(b) : "v"(p) : "memory");
}
DEVINL void gl_store8_coh(void* p, u64 v) {
  asm volatile("global_store_dwordx2 %0, %1, off sc0 sc1"
               :: "v"(p), "v"(v) : "memory");
}

// One pipeline stage: layer l for one 16-row batch tile, all 512 steps.
//
// Step order (R9, proven):
//   ph1 h-store(t-1)  ph2 x-load issue(t+2)  ph3 h-MFMAs  ph4 gates+h-write
//   ph5 counted vmcnt ph6 x-MFMAs(t+1, C=bias_acc)        ph7 barrier
//
// R11 changes vs R9:
//  * weights/bias pre-scaled by -log2(e) (sigma gates) / -2log2(e) (g gate):
//    exp2 args come straight from the MFMA accumulator (16 fewer v_mul/step).
//  * MFMA C-operand seeded from persistent bias_acc (16 fewer v_mov/step).
//  * Wave0-only flag discipline (barrier-transitive): every step ends in
//    s_barrier, so wave0 blocking in wait_ge holds the whole block. Loads in
//    steps B..B+1 touch x<=B+3, which boundary B-2's check (tgt=(B-2)+5=B+3)
//    covered BEFORE the barrier those loads are issued behind. Back-pressure:
//    stores in steps B-8..B-1 hit slots <= B-2 needing cons >= B-130; the
//    B-16 check guarantees cons >= B-120.
template<int LIN, int H, int XMODE, bool PROD, bool CONS, bool LAST>
DEVINL void run_layer(const float* __restrict__ wih, const float* __restrict__ whh,
                      const float* __restrict__ bih, const float* __restrict__ bhh,
                      const float* __restrict__ x0,
                      const f16_t* __restrict__ sin_, f16_t* __restrict__ sout_,
                      const int* prog_up, int* cons_self,
                      int* prog_self, const int* cons_down,
                      int b0, f16_t* hbA, f16_t* hbB, float* h_fin)
{
  constexpr int H16   = H/16;
  constexpr int KX    = (XMODE==0) ? 1 : LIN/32;
  constexpr int KH    = H/32;
  constexpr int SLI   = 16*LIN;               // input slot elems (XMODE1)
  constexpr int SLO   = 16*H;                 // output slot elems
  constexpr int NLOAD = (XMODE==0) ? 2 : KX;  // asm load ops per step

  constexpr float K1 = 1.442695040888963f;   // log2(e)
  constexpr float K2 = 2.885390081777927f;   // 2*log2(e)

  const int tid = (int)threadIdx.x;
  const int wv = tid >> 6, ln = tid & 63, lr = ln & 15, lg = ln >> 4;
  const bool act = (wv < H16);
  const int j = wv*16 + lr;                    // this lane's hidden col

  // ---- weight B-fragments, PRE-SCALED: gate g scaled by -K2 (g==2) or -K1 ----
  f16x8 wf[4][KX+KH];
  f32x4 bias_acc[4];                           // persistent MFMA C-init
  if (act) {
    #pragma unroll
    for (int g = 0; g < 4; ++g) {
      const float sc = (g == 2) ? -K2 : -K1;
      const int n = g*H + j;
      const float bv = (bih[n] + bhh[n]) * sc;
      bias_acc[g] = f32x4{bv, bv, bv, bv};
      #pragma unroll
      for (int kt = 0; kt < KX; ++kt)
        #pragma unroll
        for (int i = 0; i < 8; ++i) {
          const int k = kt*32 + lg*8 + i;
          wf[g][kt][i] = (f16_t)((k < LIN) ? wih[n*LIN + k]*sc : 0.0f);  // L0 pads 8->32
        }
      #pragma unroll
      for (int kt = 0; kt < KH; ++kt)
        #pragma unroll
        for (int i = 0; i < 8; ++i)
          wf[g][KX+kt][i] = (f16_t)(whh[n*H + kt*32 + lg*8 + i]*sc);
    }
  }

  for (int z = tid; z < BT*H; z += NW*64) { hbA[z] = (f16_t)0.0f; hbB[z] = (f16_t)0.0f; }
  float c4[4] = {0.0f, 0.0f, 0.0f, 0.0f};

  auto issue_loads = [&](int t, f16x8 (&xr)[KX], f32x4 (&pr)[2]) {
    if constexpr (XMODE == 0) {
      const float* p = x0 + ((size_t)(b0+lr)*SEQ + t)*8;
      gl_load32_f32(p, pr[0], pr[1]);
    } else {
      const f16_t* base = sin_ + (size_t)(t & (RING-1))*SLI + lr*LIN;
      #pragma unroll
      for (int kt = 0; kt < KX; ++kt) {
        const int chunk = ((kt*4 + lg) ^ (lr & 7)) * 8;    // swizzle folded in
        gl_load16_coh(base + chunk, xr[kt]);
      }
    }
  };

  // ---- initial consumer gate (all waves; covers prologue + early steps x<=9) ----
  int fl_up = 0, fl_dn = 0;
  if constexpr (CONS) { wait_ge(prog_up, 9); fl_up = ld_flag(prog_up); }

  // ---- prologue: accA = bias + x_0 path; then issue loads for x_1 ----
  f32x4 accA[4], accB[4];
  f16x8 xA[KX], xB[KX];
  f32x4 pA[2], pB[2];
  if (act) {
    f16x8 x0f[KX]; f32x4 p0[2];
    issue_loads(0, x0f, p0);
    asm volatile("s_waitcnt vmcnt(0)" ::: "memory");
    __builtin_amdgcn_sched_barrier(0);
    if constexpr (XMODE == 0) {
      f16x8 xf;
      #pragma unroll
      for (int i = 0; i < 8; ++i) {
        const float v = (lg == 0) ? ((i < 4) ? p0[0][i] : p0[1][i-4]) : 0.0f;
        xf[i] = (f16_t)v;
      }
      #pragma unroll
      for (int g = 0; g < 4; ++g) accA[g] = mfma16(xf, wf[g][0], bias_acc[g]);
    } else {
      #pragma unroll
      for (int g = 0; g < 4; ++g) accA[g] = mfma16(x0f[0], wf[g][0], bias_acc[g]);
      #pragma unroll
      for (int kt = 1; kt < KX; ++kt)
        #pragma unroll
        for (int g = 0; g < 4; ++g) accA[g] = mfma16(x0f[kt], wf[g][kt], accA[g]);
    }
    issue_loads(1, xA, pA);
  }
  __syncthreads();

  auto step = [&](int t, f32x4 (&ac)[4], f32x4 (&an)[4],
                  f16x8 (&xc)[KX], f32x4 (&pc)[2],
                  f16x8 (&xn)[KX], f32x4 (&pn)[2],
                  f16_t* hr, f16_t* hw) {
    if (act) {
      // ph1: stream-copy h(t-1) FIRST (store stays oldest VMEM of the step)
      if constexpr (PROD) {
        if (t >= 1) {
          const u64 v = *(const u64*)(hr + (size_t)tid*4);
          gl_store8_coh((u64*)(sout_ + (size_t)((t-1) & (RING-1))*SLO) + tid, v);
        }
      }
      // ph2: issue x prefetch for t+2
      const int tf = (t+2 < SEQ) ? t+2 : SEQ-1;
      issue_loads(tf, xn, pn);
      // ph3: h-path MFMAs (LDS only)
      #pragma unroll
      for (int kt = 0; kt < KH; ++kt) {
        const int chunk = ((kt*4 + lg) ^ (lr & 7)) * 8;
        const f16x8 ah = *(const f16x8*)&hr[lr*H + chunk];
        #pragma unroll
        for (int g = 0; g < 4; ++g) ac[g] = mfma16(ah, wf[g][KX+kt], ac[g]);
      }
      // ph4: gates — preacts already exp2-scaled by the weights; 5 exp2 + 2 rcp
      #pragma unroll
      for (int r = 0; r < 4; ++r) {
        const int b = lg*4 + r;
        const float ei = __builtin_amdgcn_exp2f(ac[0][r]);
        const float ef = __builtin_amdgcn_exp2f(ac[1][r]);
        const float eg = __builtin_amdgcn_exp2f(fminf(ac[2][r], 121.f));
        const float eo = __builtin_amdgcn_exp2f(ac[3][r]);
        const float pig = (1.f + ei)*(1.f + eg);
        // cv = c/(1+ef) + (1-eg)/pig  via common denominator (one rcp)
        const float cv = (c4[r]*pig + (1.f - eg)*(1.f + ef))
                         * __builtin_amdgcn_rcpf((1.f + ef)*pig);
        c4[r] = cv;
        const float ec = __builtin_amdgcn_exp2f(-K2*fmaxf(cv, -42.f));
        const float h  = (1.f - ec) * __builtin_amdgcn_rcpf((1.f + eo)*(1.f + ec));
        hw[b*H + (j ^ ((b & 7) << 3))] = (f16_t)h;
        if constexpr (LAST) if (t == SEQ-1) h_fin[b*64 + j] = h;
      }
      // ph5: counted wait — retires x(t+1) loads (issued t-1) + stores >=2 old
      if constexpr (PROD) {
        if (t >= 1) { asm volatile("s_waitcnt vmcnt(%0)" :: "i"(NLOAD+1) : "memory"); }
        else        { asm volatile("s_waitcnt vmcnt(%0)" :: "i"(NLOAD)   : "memory"); }
      } else {
        asm volatile("s_waitcnt vmcnt(%0)" :: "i"(NLOAD) : "memory");
      }
      __builtin_amdgcn_sched_barrier(0);
      // ph6: next-step acc: x_{t+1} path, C seeded by bias_acc
      if constexpr (XMODE == 0) {
        f16x8 xf;
        #pragma unroll
        for (int i = 0; i < 8; ++i) {
          const float v = (lg == 0) ? ((i < 4) ? pc[0][i] : pc[1][i-4]) : 0.0f;
          xf[i] = (f16_t)v;
        }
        #pragma unroll
        for (int g = 0; g < 4; ++g) an[g] = mfma16(xf, wf[g][0], bias_acc[g]);
      } else {
        #pragma unroll
        for (int g = 0; g < 4; ++g) an[g] = mfma16(xc[0], wf[g][0], bias_acc[g]);
        #pragma unroll
        for (int kt = 1; kt < KX; ++kt)
          #pragma unroll
          for (int g = 0; g < 4; ++g) an[g] = mfma16(xc[kt], wf[g][kt], an[g]);
      }
    }
    sync_raw();   // ph7
  };

  // 2-step chunks; drain-free publishes; wave0-only consumer/back-pressure gates
  for (int t0 = 0; t0 < SEQ; t0 += 2) {
    if (t0 > 0) {
      if constexpr (PROD) if (tid == 0) st_flag(prog_self, t0 - 3);
      if constexpr (CONS) {
        if ((t0 & 15) == 0 && tid == 0) st_flag(cons_self, t0 - 1);
        if (wv == 0) {
          const int tgt = (t0+5 < SEQ-1) ? t0+5 : SEQ-1;
          if (fl_up < tgt) wait_ge(prog_up, tgt);
          fl_up = ld_flag(prog_up);               // prefetch next boundary
        }
      }
      if constexpr (PROD) {
        if (t0 >= 104 && (t0 & 7) == 0 && wv == 0) {  // ring slot-reuse safety
          const int tgt2 = t0 - 104;
          if (fl_dn < tgt2) wait_ge(cons_down, tgt2);
          fl_dn = ld_flag(cons_down);
        }
      }
    }
    step(t0,   accA, accB, xA, pA, xB, pB, hbB, hbA);
    step(t0+1, accB, accA, xB, pB, xA, pA, hbA, hbB);
  }

  // EPILOGUE: stream h(SEQ-1) (loop's shifted copy never emits it). t=511 odd -> hbB.
  if constexpr (PROD) {
    if (act) {
      const u64 v = *(const u64*)(hbB + (size_t)tid*4);
      gl_store8_coh((u64*)(sout_ + (size_t)((SEQ-1) & (RING-1))*SLO) + tid, v);
    }
  }
  sync_full();
  if (tid == 0) {
    if constexpr (PROD) st_flag(prog_self, SEQ);
    if constexpr (CONS) st_flag(cons_self, SEQ);
  }
}

extern "C" __global__ void lstm_init_flags(int* f) {
  const int i = (int)blockIdx.x * (int)blockDim.x + (int)threadIdx.x;
  if (i < 6144) f[i] = 0;
}

// 256 blocks: (bid&3)=layer, (bid>>2)=batch tile. One block/CU -> all resident.
extern "C" __global__ __launch_bounds__(512, 2)
void lstm_pipe(const float* __restrict__ xin,
  const float* w0i, const float* w0h, const float* b0i, const float* b0h,
  const float* w1i, const float* w1h, const float* b1i, const float* b1h,
  const float* w2i, const float* w2h, const float* b2i, const float* b2h,
  const float* w3i, const float* w3h, const float* b3i, const float* b3h,
  const float* __restrict__ lw, const float* __restrict__ lb,
  float* __restrict__ out, f16_t* ws16, int* flags)
{
  __shared__ __align__(16) f16_t hbuf0[BT*128];
  __shared__ __align__(16) f16_t hbuf1[BT*128];
  __shared__ float h_fin[BT*64];

  const int bid = (int)blockIdx.x;
  const int l = bid & 3, bt = bid >> 2, b0 = bt * BT;
  int* progf = flags;
  int* consf = flags + 3*64*16;
  int* P0 = progf + (0*64+bt)*16; int* C0 = consf + (0*64+bt)*16;
  int* P1 = progf + (1*64+bt)*16; int* C1 = consf + (1*64+bt)*16;
  int* P2 = progf + (2*64+bt)*16; int* C2 = consf + (2*64+bt)*16;

  f16_t* s0 = ws16 + S0_OFF + (size_t)bt * RING * 2048;
  f16_t* s1 = ws16 + S1_OFF + (size_t)bt * RING * 2048;
  f16_t* s2 = ws16 + S2_OFF + (size_t)bt * RING * 1024;

  if (l == 0) {
    run_layer<8,   128, 0, true,  false, false>(w0i,w0h,b0i,b0h, xin, nullptr, s0,
        nullptr, nullptr, P0, C0, b0, hbuf0, hbuf1, h_fin);
  } else if (l == 1) {
    run_layer<128, 128, 1, true,  true,  false>(w1i,w1h,b1i,b1h, nullptr, s0, s1,
        P0, C0, P1, C1, b0, hbuf0, hbuf1, h_fin);
  } else if (l == 2) {
    run_layer<128, 64,  1, true,  true,  false>(w2i,w2h,b2i,b2h, nullptr, s1, s2,
        P1, C1, P2, C2, b0, hbuf0, hbuf1, h_fin);
  } else {
    run_layer<64,  64,  1, false, true,  true >(w3i,w3h,b3i,b3h, nullptr, s2, nullptr,
        P2, C2, nullptr, nullptr, b0, hbuf0, hbuf1, h_fin);
    // final linear: out[b] = h_fin[b,:] . lw + lb
    const int wv = (int)threadIdx.x >> 6;
    const int ln = (int)threadIdx.x & 63;
    #pragma unroll
    for (int rr = 0; rr < 2; ++rr) {
      const int row = wv*2 + rr;
      float v = h_fin[row*64 + ln] * lw[ln];
      #pragma unroll
      for (int m = 32; m >= 1; m >>= 1) v += __shfl_xor(v, m, 64);
      if (ln == 0) out[b0 + row] = v + lb[0];
    }
  }
}

extern "C" void kernel_launch(void* const* d_in, const int* in_sizes, int n_in,
                              void* d_out, int out_size, void* d_ws, size_t ws_size,
                              hipStream_t stream) {
  const float* xin = (const float*)d_in[0];
  const float* w0i = (const float*)d_in[1];
  const float* w0h = (const float*)d_in[2];
  const float* b0i = (const float*)d_in[3];
  const float* b0h = (const float*)d_in[4];
  const float* w1i = (const float*)d_in[5];
  const float* w1h = (const float*)d_in[6];
  const float* b1i = (const float*)d_in[7];
  const float* b1h = (const float*)d_in[8];
  const float* w2i = (const float*)d_in[9];
  const float* w2h = (const float*)d_in[10];
  const float* b2i = (const float*)d_in[11];
  const float* b2h = (const float*)d_in[12];
  const float* w3i = (const float*)d_in[13];
  const float* w3h = (const float*)d_in[14];
  const float* b3i = (const float*)d_in[15];
  const float* b3h = (const float*)d_in[16];
  const float* lw  = (const float*)d_in[17];
  const float* lb  = (const float*)d_in[18];
  float* out = (float*)d_out;

  f16_t* ws16 = (f16_t*)d_ws;                       // ~80 MB streams
  int* flags  = (int*)((char*)d_ws + FLAG_OFF_B);   // 24 KB flags

  lstm_init_flags<<<12, 512, 0, stream>>>(flags);   // re-zero per launch (replay-safe)
  lstm_pipe<<<256, 512, 0, stream>>>(xin,
      w0i,w0h,b0i,b0h, w1i,w1h,b1i,b1h, w2i,w2h,b2i,b2h, w3i,w3h,b3i,b3h,
      lw, lb, out, ws16, flags);
}